// Round 1
// baseline (564.608 us; speedup 1.0000x reference)
//
#include <hip/hip_runtime.h>
#include <hip/hip_bf16.h>

#define NUM_CAT 32
#define IN_DIM 1024
#define HID_DIM 2048
#define T_DIM 256
#define B_DIM 64

typedef __attribute__((ext_vector_type(4))) float floatx4;
typedef __attribute__((ext_vector_type(8))) short shortx8;   // 8 bf16 (4 VGPRs)

__device__ __forceinline__ unsigned short f2bf(float f) {
  // round-to-nearest-even fp32 -> bf16
  unsigned u = __builtin_bit_cast(unsigned, f);
  u += 0x7FFFu + ((u >> 16) & 1u);
  return (unsigned short)(u >> 16);
}

// async global->LDS, 16B per lane. LDS dest must be linear in lane (wave-uniform
// base + lane*16); swizzled layouts are achieved by permuting the GLOBAL source
// address (guide rule #21 / m173).
#define GLDS16(g, l) __builtin_amdgcn_global_load_lds( \
    (const __attribute__((address_space(1))) unsigned int*)(g), \
    (__attribute__((address_space(3))) unsigned int*)(l), 16, 0, 0)

// =====================================================================
// Prepass 1: W [c][k][n] fp32  ->  Wt [c][n][k] bf16   (convert + transpose,
// each element touched exactly once; LDS-tiled so both sides coalesce)
// =====================================================================
__global__ __launch_bounds__(256) void conv_w_kernel(
    const float* __restrict__ W, unsigned short* __restrict__ Wt) {
  __shared__ unsigned short t[64][66];   // +2 pad: column walk steps 33 words -> 2-way max
  const int ntile = blockIdx.x;   // 0..31  (n / 64)
  const int ktile = blockIdx.y;   // 0..15  (k / 64)
  const int c     = blockIdx.z;   // 0..31
  const int tid = threadIdx.x;
  const int r  = tid >> 4;          // 0..15
  const int c4 = (tid & 15) * 4;    // 0..60

  const float* src = W + ((size_t)c * IN_DIM + (size_t)ktile * 64) * HID_DIM + (size_t)ntile * 64;
  #pragma unroll
  for (int p = 0; p < 4; ++p) {
    const int k = p * 16 + r;
    const float4 v = *reinterpret_cast<const float4*>(src + (size_t)k * HID_DIM + c4);
    t[k][c4 + 0] = f2bf(v.x);
    t[k][c4 + 1] = f2bf(v.y);
    t[k][c4 + 2] = f2bf(v.z);
    t[k][c4 + 3] = f2bf(v.w);
  }
  __syncthreads();
  unsigned short* dst = Wt + ((size_t)c * HID_DIM + (size_t)ntile * 64) * IN_DIM + (size_t)ktile * 64;
  #pragma unroll
  for (int p = 0; p < 4; ++p) {
    const int n = p * 16 + r;
    ushort4 o;
    o.x = t[c4 + 0][n];
    o.y = t[c4 + 1][n];
    o.z = t[c4 + 2][n];
    o.w = t[c4 + 3][n];
    *reinterpret_cast<ushort4*>(dst + (size_t)n * IN_DIM + c4) = o;  // 16 thr -> 128B contiguous
  }
}

// =====================================================================
// Prepass 2: x fp32 -> bf16, elementwise, float4 in / ushort4 out
// =====================================================================
__global__ __launch_bounds__(256) void conv_x_kernel(
    const float* __restrict__ x, unsigned short* __restrict__ xb) {
  const int total4 = B_DIM * T_DIM * IN_DIM / 4;
  for (int i = blockIdx.x * blockDim.x + threadIdx.x; i < total4;
       i += gridDim.x * blockDim.x) {
    const float4 v = reinterpret_cast<const float4*>(x)[i];
    ushort4 h;
    h.x = f2bf(v.x); h.y = f2bf(v.y); h.z = f2bf(v.z); h.w = f2bf(v.w);
    reinterpret_cast<ushort4*>(xb)[i] = h;
  }
}

// =====================================================================
// Main GEMM: pure-bf16, 128x128 tile, BK=64, 4 waves (2x2), m97 structure:
// global_load_lds dwordx4 staging + XOR-swizzled ds_read_b128 fragments.
// =====================================================================
__global__ __launch_bounds__(256) void cat_gemm_bf16_kernel(
    const unsigned short* __restrict__ xb, const int* __restrict__ cat_ids,
    const unsigned short* __restrict__ Wt, const float* __restrict__ bias,
    float* __restrict__ out) {
  const int nt = blockIdx.x;   // 0..15  (hidden tiles)
  const int mt = blockIdx.y;   // 0..1   (token tiles)
  const int b  = blockIdx.z;   // 0..63  (batch)
  const int tid = threadIdx.x;
  const int c = cat_ids[b];

  // A: [m][k] 128 rows x 128B; B: [n][k] 128 rows x 128B. Linear (no pad) so
  // global_load_lds works; bank spread comes from the XOR swizzle.
  __shared__ __attribute__((aligned(16))) unsigned short As[128 * 64];  // 16 KB
  __shared__ __attribute__((aligned(16))) unsigned short Bs[128 * 64];  // 16 KB

  const int lane = tid & 63;
  const int wv   = tid >> 6;         // wave 0..3 -> 2x2
  const int wm   = (wv >> 1) * 64;
  const int wn   = (wv & 1) * 64;
  const int l16  = lane & 15;
  const int quad = lane >> 4;

  // staging decomposition: linear LDS byte offset o = call*4096 + tid*16
  const int row_st = tid >> 3;            // row within 32-row group
  const int kb_st  = (tid & 7) * 16;      // byte within 128B row (pre-XOR)

  const char* xa = (const char*)xb + (size_t)(b * T_DIM + mt * 128) * (IN_DIM * 2);
  const char* wa = (const char*)Wt + ((size_t)c * HID_DIM + (size_t)nt * 128) * (IN_DIM * 2);

  floatx4 acc[4][4] = {};

  for (int ks = 0; ks < IN_DIM / 64; ++ks) {
    const size_t kbase = (size_t)ks * 128;   // byte offset along k

    // ---- stage A and B tiles: 16KB each = 4 x (256 lanes x 16B)
    // source k-byte is XORed with (row&7)<<4 so that a matching XOR on the
    // ds_read side yields conflict-free banks (both-sides involution).
    #pragma unroll
    for (int i = 0; i < 4; ++i) {
      const int m  = i * 32 + row_st;
      const int kb = kb_st ^ ((m & 7) << 4);
      GLDS16(xa + (size_t)m * 2048 + kbase + kb, (char*)As + i * 4096 + tid * 16);
      GLDS16(wa + (size_t)m * 2048 + kbase + kb, (char*)Bs + i * 4096 + tid * 16);
    }

    __syncthreads();   // compiler emits vmcnt(0) drain here (m97 structure)

    // ---- fragments: contiguous-k ds_read_b128, swizzled address
    shortx8 af[4][2], bfr[4][2];
    #pragma unroll
    for (int i = 0; i < 4; ++i) {
      const int row = wm + i * 16 + l16;
      const int sw  = (row & 7) << 4;
      af[i][0] = *reinterpret_cast<const shortx8*>((const char*)As + row * 128 + ((quad * 16) ^ sw));
      af[i][1] = *reinterpret_cast<const shortx8*>((const char*)As + row * 128 + ((64 + quad * 16) ^ sw));
    }
    #pragma unroll
    for (int j = 0; j < 4; ++j) {
      const int row = wn + j * 16 + l16;
      const int sw  = (row & 7) << 4;
      bfr[j][0] = *reinterpret_cast<const shortx8*>((const char*)Bs + row * 128 + ((quad * 16) ^ sw));
      bfr[j][1] = *reinterpret_cast<const shortx8*>((const char*)Bs + row * 128 + ((64 + quad * 16) ^ sw));
    }

    // ---- 32 MFMA per wave per K-step (2 k-subtiles x 4x4 frags)
    #pragma unroll
    for (int s = 0; s < 2; ++s)
      #pragma unroll
      for (int i = 0; i < 4; ++i)
        #pragma unroll
        for (int j = 0; j < 4; ++j)
          acc[i][j] = __builtin_amdgcn_mfma_f32_16x16x32_bf16(af[i][s], bfr[j][s], acc[i][j], 0, 0, 0);

    __syncthreads();
  }

  // ---- epilogue: C/D layout col=l16, row=quad*4+r (harness-verified mapping)
  float* outp = out + ((size_t)b * T_DIM + (size_t)mt * 128) * HID_DIM + nt * 128;
  const float* bp = bias + (size_t)c * HID_DIM + nt * 128;
  #pragma unroll
  for (int j = 0; j < 4; ++j) {
    const float bj = bp[wn + j * 16 + l16];
    #pragma unroll
    for (int i = 0; i < 4; ++i) {
      #pragma unroll
      for (int r = 0; r < 4; ++r) {
        const int m = wm + i * 16 + quad * 4 + r;
        outp[(size_t)m * HID_DIM + wn + j * 16 + l16] = acc[i][j][r] + bj;
      }
    }
  }
}

// =====================================================================
// Fallback (harness-verified previous kernel, 522.9us): used only when the
// workspace is too small for the bf16 prepass buffers.
// =====================================================================
__global__ __launch_bounds__(256) void cat_linear_fallback_kernel(
    const float* __restrict__ x, const int* __restrict__ cat_ids,
    const float* __restrict__ W, const float* __restrict__ bias,
    float* __restrict__ out) {
  const int nt = blockIdx.x;
  const int mt = blockIdx.y;
  const int b  = blockIdx.z;
  const int tid = threadIdx.x;
  const int c = cat_ids[b];

  const int n0 = nt * 128;
  const float* xbp = x + ((size_t)b * T_DIM + (size_t)mt * 128) * IN_DIM;
  const float* Wc = W + (size_t)c * IN_DIM * HID_DIM + n0;

  __shared__ __attribute__((aligned(16))) unsigned short As[128 * 32];
  __shared__ __attribute__((aligned(16))) unsigned short Bs[128 * 40];

  const int lane = tid & 63;
  const int wv   = tid >> 6;
  const int wm   = (wv >> 1) * 64;
  const int wn   = (wv & 1) * 64;
  const int l16  = lane & 15;
  const int quad = lane >> 4;

  floatx4 acc[4][4] = {};

  const int ar = tid >> 3;
  const int ac = (tid & 7) * 4;
  const int kp = tid >> 4;
  const int bn = (tid & 15) * 4;

  for (int ks = 0; ks < IN_DIM / 32; ++ks) {
    const int k0 = ks * 32;
    #pragma unroll
    for (int p = 0; p < 4; ++p) {
      const int m = ar + p * 32;
      const float4 v = *reinterpret_cast<const float4*>(xbp + (size_t)m * IN_DIM + k0 + ac);
      ushort4 h;
      h.x = f2bf(v.x); h.y = f2bf(v.y); h.z = f2bf(v.z); h.w = f2bf(v.w);
      *reinterpret_cast<ushort4*>(&As[m * 32 + ac]) = h;
    }
    #pragma unroll
    for (int q = 0; q < 2; ++q) {
      const int n = bn + q * 64;
      const float4 v0 = *reinterpret_cast<const float4*>(Wc + (size_t)(k0 + 2 * kp)     * HID_DIM + n);
      const float4 v1 = *reinterpret_cast<const float4*>(Wc + (size_t)(k0 + 2 * kp + 1) * HID_DIM + n);
      unsigned w;
      w = (unsigned)f2bf(v0.x) | ((unsigned)f2bf(v1.x) << 16);
      *reinterpret_cast<unsigned*>(&Bs[(n + 0) * 40 + 2 * kp]) = w;
      w = (unsigned)f2bf(v0.y) | ((unsigned)f2bf(v1.y) << 16);
      *reinterpret_cast<unsigned*>(&Bs[(n + 1) * 40 + 2 * kp]) = w;
      w = (unsigned)f2bf(v0.z) | ((unsigned)f2bf(v1.z) << 16);
      *reinterpret_cast<unsigned*>(&Bs[(n + 2) * 40 + 2 * kp]) = w;
      w = (unsigned)f2bf(v0.w) | ((unsigned)f2bf(v1.w) << 16);
      *reinterpret_cast<unsigned*>(&Bs[(n + 3) * 40 + 2 * kp]) = w;
    }
    __syncthreads();

    shortx8 af[4], bfr[4];
    #pragma unroll
    for (int i = 0; i < 4; ++i)
      af[i] = *reinterpret_cast<const shortx8*>(&As[(wm + i * 16 + l16) * 32 + quad * 8]);
    #pragma unroll
    for (int j = 0; j < 4; ++j)
      bfr[j] = *reinterpret_cast<const shortx8*>(&Bs[(wn + j * 16 + l16) * 40 + quad * 8]);

    #pragma unroll
    for (int i = 0; i < 4; ++i)
      #pragma unroll
      for (int j = 0; j < 4; ++j)
        acc[i][j] = __builtin_amdgcn_mfma_f32_16x16x32_bf16(af[i], bfr[j], acc[i][j], 0, 0, 0);

    __syncthreads();
  }

  float* outp = out + ((size_t)b * T_DIM + (size_t)mt * 128) * HID_DIM + n0;
  const float* bp = bias + (size_t)c * HID_DIM + n0;
  #pragma unroll
  for (int j = 0; j < 4; ++j) {
    const float bj = bp[wn + j * 16 + l16];
    #pragma unroll
    for (int i = 0; i < 4; ++i) {
      #pragma unroll
      for (int r = 0; r < 4; ++r) {
        const int m = wm + i * 16 + quad * 4 + r;
        outp[(size_t)m * HID_DIM + wn + j * 16 + l16] = acc[i][j][r] + bj;
      }
    }
  }
}

extern "C" void kernel_launch(void* const* d_in, const int* in_sizes, int n_in,
                              void* d_out, int out_size, void* d_ws, size_t ws_size,
                              hipStream_t stream) {
  const float* x    = (const float*)d_in[0];
  const int*   cat  = (const int*)d_in[1];
  const float* W    = (const float*)d_in[2];
  const float* bias = (const float*)d_in[3];
  float* out = (float*)d_out;

  const size_t WT_BYTES = (size_t)NUM_CAT * HID_DIM * IN_DIM * 2;  // 128 MB
  const size_t XB_BYTES = (size_t)B_DIM * T_DIM * IN_DIM * 2;      //  32 MB

  if (ws_size >= WT_BYTES + XB_BYTES) {
    unsigned short* Wt  = (unsigned short*)d_ws;
    unsigned short* xbf = (unsigned short*)((char*)d_ws + WT_BYTES);

    // prepass: convert W (transpose) and x to bf16 — each element exactly once
    hipLaunchKernelGGL(conv_w_kernel, dim3(HID_DIM / 64, IN_DIM / 64, NUM_CAT),
                       dim3(256), 0, stream, W, Wt);
    hipLaunchKernelGGL(conv_x_kernel, dim3(2048), dim3(256), 0, stream, x, xbf);

    // main GEMM: (16, 2, 64) = 2048 blocks of 256
    hipLaunchKernelGGL(cat_gemm_bf16_kernel, dim3(HID_DIM / 128, T_DIM / 128, B_DIM),
                       dim3(256), 0, stream, xbf, cat, Wt, bias, out);
  } else {
    hipLaunchKernelGGL(cat_linear_fallback_kernel,
                       dim3(HID_DIM / 128, T_DIM / 128, B_DIM), dim3(256), 0, stream,
                       x, cat, W, bias, out);
  }
}

// Round 2
// 548.042 us; speedup vs baseline: 1.0302x; 1.0302x over previous
//
#include <hip/hip_runtime.h>
#include <hip/hip_bf16.h>

#define NUM_CAT 32
#define IN_DIM 1024
#define HID_DIM 2048
#define T_DIM 256
#define B_DIM 64

typedef __attribute__((ext_vector_type(4))) float floatx4;
typedef __attribute__((ext_vector_type(8))) short shortx8;   // 8 bf16 (4 VGPRs)

__device__ __forceinline__ unsigned short f2bf(float f) {
  // round-to-nearest-even fp32 -> bf16
  unsigned u = __builtin_bit_cast(unsigned, f);
  u += 0x7FFFu + ((u >> 16) & 1u);
  return (unsigned short)(u >> 16);
}

__device__ __forceinline__ unsigned pack2(float a, float b) {
  return (unsigned)f2bf(a) | ((unsigned)f2bf(b) << 16);
}

// =====================================================================
// Fused kernel: fp32 x / W converted to bf16 IN-REGISTER during staging,
// written to the XOR-swizzled LDS layout verified in Round 1, then the
// proven BK=64 / 2-subtile / 4-wave MFMA loop. No workspace (avoids the
// harness's 1 GiB re-poison fills that dominated Round 1's timing).
// =====================================================================
__global__ __launch_bounds__(256) void cat_linear_fused_kernel(
    const float* __restrict__ x, const int* __restrict__ cat_ids,
    const float* __restrict__ W, const float* __restrict__ bias,
    float* __restrict__ out) {
  const int nt = blockIdx.x;   // 0..15  (hidden tiles)
  const int mt = blockIdx.y;   // 0..1   (token tiles)
  const int b  = blockIdx.z;   // 0..63  (batch)
  const int tid = threadIdx.x;
  const int c = cat_ids[b];

  // A: [m 0..127][k 0..63] bf16, 128B rows; B: [n 0..127][k 0..63] bf16.
  // Both linear with the (row&7)<<4 byte-XOR swizzle applied at BOTH the
  // ds_write and ds_read side (involution) -> conflict-free b128 reads.
  __shared__ __attribute__((aligned(16))) unsigned short As[128 * 64];  // 16 KB
  __shared__ __attribute__((aligned(16))) unsigned short Bs[128 * 64];  // 16 KB

  const int lane = tid & 63;
  const int wv   = tid >> 6;         // wave 0..3 -> 2x2
  const int wm   = (wv >> 1) * 64;
  const int wn   = (wv & 1) * 64;
  const int l16  = lane & 15;
  const int quad = lane >> 4;

  // A staging: thread -> (row ar + i*32, k-bytes au*16..au*16+15)
  const int ar = tid >> 3;           // 0..31
  const int au = tid & 7;            // 16B unit within 128B row
  // B staging: thread -> (n = bn4..bn4+3, k = bk8..bk8+7)
  const int bn4 = (tid & 31) * 4;    // 0..124
  const int bk8 = (tid >> 5) * 8;    // 0..56

  const float* xb = x + ((size_t)b * T_DIM + (size_t)mt * 128) * IN_DIM;
  const float* Wc = W + (size_t)c * IN_DIM * HID_DIM + (size_t)nt * 128;

  floatx4 acc[4][4] = {};

  for (int ks = 0; ks < IN_DIM / 64; ++ks) {
    const int k0 = ks * 64;

    // ---- stage A: 128x64 fp32 -> bf16, row-contiguous. Lanes 0..7 cover one
    // full 256B row segment -> perfectly coalesced; ds_write_b128 per group.
    #pragma unroll
    for (int i = 0; i < 4; ++i) {
      const int m = i * 32 + ar;
      const float* ap = xb + (size_t)m * IN_DIM + k0 + au * 8;
      const float4 v0 = *reinterpret_cast<const float4*>(ap);
      const float4 v1 = *reinterpret_cast<const float4*>(ap + 4);
      union { shortx8 s8; unsigned u[4]; } pk;
      pk.u[0] = pack2(v0.x, v0.y);
      pk.u[1] = pack2(v0.z, v0.w);
      pk.u[2] = pack2(v1.x, v1.y);
      pk.u[3] = pack2(v1.z, v1.w);
      *reinterpret_cast<shortx8*>(
          (char*)As + m * 128 + ((au * 16) ^ ((m & 7) << 4))) = pk.s8;
    }

    // ---- stage B: 64x128 fp32 tile of W [k][n] -> transpose -> Bs [n][k].
    // Thread loads 8 k-rows x 4 n (float4, coalesced: 32 lanes = 512B/row),
    // packs each n-column of 8 k's into one shortx8 -> 4 ds_write_b128.
    {
      const float* wp = Wc + (size_t)(k0 + bk8) * HID_DIM + bn4;
      const float4 w0 = *reinterpret_cast<const float4*>(wp + 0 * HID_DIM);
      const float4 w1 = *reinterpret_cast<const float4*>(wp + 1 * HID_DIM);
      const float4 w2 = *reinterpret_cast<const float4*>(wp + 2 * HID_DIM);
      const float4 w3 = *reinterpret_cast<const float4*>(wp + 3 * HID_DIM);
      const float4 w4 = *reinterpret_cast<const float4*>(wp + 4 * HID_DIM);
      const float4 w5 = *reinterpret_cast<const float4*>(wp + 5 * HID_DIM);
      const float4 w6 = *reinterpret_cast<const float4*>(wp + 6 * HID_DIM);
      const float4 w7 = *reinterpret_cast<const float4*>(wp + 7 * HID_DIM);
      union { shortx8 s8; unsigned u[4]; } pk;
      // n = bn4 + 0  (static component extracts -> stays in registers)
      pk.u[0] = pack2(w0.x, w1.x); pk.u[1] = pack2(w2.x, w3.x);
      pk.u[2] = pack2(w4.x, w5.x); pk.u[3] = pack2(w6.x, w7.x);
      *reinterpret_cast<shortx8*>(
          (char*)Bs + (bn4 + 0) * 128 + ((bk8 * 2) ^ (((bn4 + 0) & 7) << 4))) = pk.s8;
      // n = bn4 + 1
      pk.u[0] = pack2(w0.y, w1.y); pk.u[1] = pack2(w2.y, w3.y);
      pk.u[2] = pack2(w4.y, w5.y); pk.u[3] = pack2(w6.y, w7.y);
      *reinterpret_cast<shortx8*>(
          (char*)Bs + (bn4 + 1) * 128 + ((bk8 * 2) ^ (((bn4 + 1) & 7) << 4))) = pk.s8;
      // n = bn4 + 2
      pk.u[0] = pack2(w0.z, w1.z); pk.u[1] = pack2(w2.z, w3.z);
      pk.u[2] = pack2(w4.z, w5.z); pk.u[3] = pack2(w6.z, w7.z);
      *reinterpret_cast<shortx8*>(
          (char*)Bs + (bn4 + 2) * 128 + ((bk8 * 2) ^ (((bn4 + 2) & 7) << 4))) = pk.s8;
      // n = bn4 + 3
      pk.u[0] = pack2(w0.w, w1.w); pk.u[1] = pack2(w2.w, w3.w);
      pk.u[2] = pack2(w4.w, w5.w); pk.u[3] = pack2(w6.w, w7.w);
      *reinterpret_cast<shortx8*>(
          (char*)Bs + (bn4 + 3) * 128 + ((bk8 * 2) ^ (((bn4 + 3) & 7) << 4))) = pk.s8;
    }

    __syncthreads();

    // ---- fragments + MFMA, split by k-subtile to cap VGPR pressure.
    // Addressing identical to the Round-1 harness-verified GEMM.
    #pragma unroll
    for (int s = 0; s < 2; ++s) {
      shortx8 af[4], bfr[4];
      #pragma unroll
      for (int i = 0; i < 4; ++i) {
        const int row = wm + i * 16 + l16;
        const int sw  = (row & 7) << 4;
        af[i] = *reinterpret_cast<const shortx8*>(
            (const char*)As + row * 128 + ((s * 64 + quad * 16) ^ sw));
      }
      #pragma unroll
      for (int j = 0; j < 4; ++j) {
        const int row = wn + j * 16 + l16;
        const int sw  = (row & 7) << 4;
        bfr[j] = *reinterpret_cast<const shortx8*>(
            (const char*)Bs + row * 128 + ((s * 64 + quad * 16) ^ sw));
      }
      #pragma unroll
      for (int i = 0; i < 4; ++i)
        #pragma unroll
        for (int j = 0; j < 4; ++j)
          acc[i][j] = __builtin_amdgcn_mfma_f32_16x16x32_bf16(af[i], bfr[j], acc[i][j], 0, 0, 0);
    }

    __syncthreads();
  }

  // ---- epilogue: C/D layout col=l16, row=quad*4+r (harness-verified mapping)
  float* outp = out + ((size_t)b * T_DIM + (size_t)mt * 128) * HID_DIM + nt * 128;
  const float* bp = bias + (size_t)c * HID_DIM + nt * 128;
  #pragma unroll
  for (int j = 0; j < 4; ++j) {
    const float bj = bp[wn + j * 16 + l16];
    #pragma unroll
    for (int i = 0; i < 4; ++i) {
      #pragma unroll
      for (int r = 0; r < 4; ++r) {
        const int m = wm + i * 16 + quad * 4 + r;
        outp[(size_t)m * HID_DIM + wn + j * 16 + l16] = acc[i][j][r] + bj;
      }
    }
  }
}

extern "C" void kernel_launch(void* const* d_in, const int* in_sizes, int n_in,
                              void* d_out, int out_size, void* d_ws, size_t ws_size,
                              hipStream_t stream) {
  const float* x    = (const float*)d_in[0];
  const int*   cat  = (const int*)d_in[1];
  const float* W    = (const float*)d_in[2];
  const float* bias = (const float*)d_in[3];
  float* out = (float*)d_out;

  // Single fused launch; d_ws deliberately untouched.
  dim3 grid(HID_DIM / 128, T_DIM / 128, B_DIM);   // (16, 2, 64) = 2048 blocks
  hipLaunchKernelGGL(cat_linear_fused_kernel, grid, dim3(256), 0, stream,
                     x, cat, W, bias, out);
}

// Round 4
// 547.023 us; speedup vs baseline: 1.0321x; 1.0019x over previous
//
#include <hip/hip_runtime.h>
#include <hip/hip_bf16.h>

#define NUM_CAT 32
#define IN_DIM 1024
#define HID_DIM 2048
#define T_DIM 256
#define B_DIM 64

typedef __attribute__((ext_vector_type(4))) float floatx4;
typedef __attribute__((ext_vector_type(8))) short shortx8;   // 8 bf16 (4 VGPRs)

// hardware packed conversion: compiler emits v_cvt_pk_bf16_f32 (RNE), 1 inst
// per pair vs ~7 for the bit-trick (this was the VALU ceiling in Round 2).
// NOTE: __hip_bfloat162 is not trivially copyable on this ROCm, so bit_cast
// is rejected; __builtin_memcpy is the portable zero-cost reinterpret.
__device__ __forceinline__ unsigned pack2(float a, float b) {
  __hip_bfloat162 h2 = __float22bfloat162_rn(make_float2(a, b));
  unsigned u;
  __builtin_memcpy(&u, &h2, 4);
  return u;
}

// Extended XOR swizzle: bits 4-6 from row&7, bit 5 additionally XORed with
// row bit 3. Verified by enumeration: A-write, B-write, A-read, B-read all
// map 8 lanes -> each of 8 16B slots (uniform = conflict-free). Must be
// applied identically on write and read (involution).
__device__ __forceinline__ int swz(int row) {
  return ((row & 7) << 4) ^ ((row & 8) << 2);
}

// =====================================================================
// Fused kernel: fp32 x / W converted to bf16 in-register during staging
// (hw cvt_pk), XOR-swizzled LDS, BK=64, 4-wave 128x128 MFMA loop.
// Structure identical to the Round-2 harness-verified kernel except:
//   1. pack2 -> v_cvt_pk_bf16_f32
//   2. swizzle gains the (row&8)<<2 term (kills B-write 4-way conflicts)
// =====================================================================
__global__ __launch_bounds__(256) void cat_linear_fused_kernel(
    const float* __restrict__ x, const int* __restrict__ cat_ids,
    const float* __restrict__ W, const float* __restrict__ bias,
    float* __restrict__ out) {
  const int nt = blockIdx.x;   // 0..15  (hidden tiles)
  const int mt = blockIdx.y;   // 0..1   (token tiles)
  const int b  = blockIdx.z;   // 0..63  (batch)
  const int tid = threadIdx.x;
  const int c = cat_ids[b];

  __shared__ __attribute__((aligned(16))) unsigned short As[128 * 64];  // 16 KB
  __shared__ __attribute__((aligned(16))) unsigned short Bs[128 * 64];  // 16 KB

  const int lane = tid & 63;
  const int wv   = tid >> 6;         // wave 0..3 -> 2x2
  const int wm   = (wv >> 1) * 64;
  const int wn   = (wv & 1) * 64;
  const int l16  = lane & 15;
  const int quad = lane >> 4;

  // A staging: thread -> (row ar + i*32, k-bytes au*16..au*16+15)
  const int ar = tid >> 3;           // 0..31
  const int au = tid & 7;            // 16B unit within 128B row
  // B staging: thread -> (n = bn4..bn4+3, k = bk8..bk8+7)
  const int bn4 = (tid & 31) * 4;    // 0..124
  const int bk8 = (tid >> 5) * 8;    // 0..56

  const float* xb = x + ((size_t)b * T_DIM + (size_t)mt * 128) * IN_DIM;
  const float* Wc = W + (size_t)c * IN_DIM * HID_DIM + (size_t)nt * 128;

  floatx4 acc[4][4] = {};

  for (int ks = 0; ks < IN_DIM / 64; ++ks) {
    const int k0 = ks * 64;

    // ---- stage A: 128x64 fp32 -> bf16, row-contiguous, coalesced.
    #pragma unroll
    for (int i = 0; i < 4; ++i) {
      const int m = i * 32 + ar;
      const float* ap = xb + (size_t)m * IN_DIM + k0 + au * 8;
      const float4 v0 = *reinterpret_cast<const float4*>(ap);
      const float4 v1 = *reinterpret_cast<const float4*>(ap + 4);
      union { shortx8 s8; unsigned u[4]; } pk;
      pk.u[0] = pack2(v0.x, v0.y);
      pk.u[1] = pack2(v0.z, v0.w);
      pk.u[2] = pack2(v1.x, v1.y);
      pk.u[3] = pack2(v1.z, v1.w);
      *reinterpret_cast<shortx8*>(
          (char*)As + m * 128 + ((au * 16) ^ swz(m))) = pk.s8;
    }

    // ---- stage B: 64x128 fp32 tile of W [k][n] -> transpose -> Bs [n][k].
    {
      const float* wp = Wc + (size_t)(k0 + bk8) * HID_DIM + bn4;
      const float4 w0 = *reinterpret_cast<const float4*>(wp + 0 * HID_DIM);
      const float4 w1 = *reinterpret_cast<const float4*>(wp + 1 * HID_DIM);
      const float4 w2 = *reinterpret_cast<const float4*>(wp + 2 * HID_DIM);
      const float4 w3 = *reinterpret_cast<const float4*>(wp + 3 * HID_DIM);
      const float4 w4 = *reinterpret_cast<const float4*>(wp + 4 * HID_DIM);
      const float4 w5 = *reinterpret_cast<const float4*>(wp + 5 * HID_DIM);
      const float4 w6 = *reinterpret_cast<const float4*>(wp + 6 * HID_DIM);
      const float4 w7 = *reinterpret_cast<const float4*>(wp + 7 * HID_DIM);
      union { shortx8 s8; unsigned u[4]; } pk;
      // n = bn4 + 0
      pk.u[0] = pack2(w0.x, w1.x); pk.u[1] = pack2(w2.x, w3.x);
      pk.u[2] = pack2(w4.x, w5.x); pk.u[3] = pack2(w6.x, w7.x);
      *reinterpret_cast<shortx8*>(
          (char*)Bs + (bn4 + 0) * 128 + ((bk8 * 2) ^ swz(bn4 + 0))) = pk.s8;
      // n = bn4 + 1
      pk.u[0] = pack2(w0.y, w1.y); pk.u[1] = pack2(w2.y, w3.y);
      pk.u[2] = pack2(w4.y, w5.y); pk.u[3] = pack2(w6.y, w7.y);
      *reinterpret_cast<shortx8*>(
          (char*)Bs + (bn4 + 1) * 128 + ((bk8 * 2) ^ swz(bn4 + 1))) = pk.s8;
      // n = bn4 + 2
      pk.u[0] = pack2(w0.z, w1.z); pk.u[1] = pack2(w2.z, w3.z);
      pk.u[2] = pack2(w4.z, w5.z); pk.u[3] = pack2(w6.z, w7.z);
      *reinterpret_cast<shortx8*>(
          (char*)Bs + (bn4 + 2) * 128 + ((bk8 * 2) ^ swz(bn4 + 2))) = pk.s8;
      // n = bn4 + 3
      pk.u[0] = pack2(w0.w, w1.w); pk.u[1] = pack2(w2.w, w3.w);
      pk.u[2] = pack2(w4.w, w5.w); pk.u[3] = pack2(w6.w, w7.w);
      *reinterpret_cast<shortx8*>(
          (char*)Bs + (bn4 + 3) * 128 + ((bk8 * 2) ^ swz(bn4 + 3))) = pk.s8;
    }

    __syncthreads();

    // ---- fragments + MFMA (addressing = Round-2 verified + same swz on read)
    #pragma unroll
    for (int s = 0; s < 2; ++s) {
      shortx8 af[4], bfr[4];
      #pragma unroll
      for (int i = 0; i < 4; ++i) {
        const int row = wm + i * 16 + l16;
        af[i] = *reinterpret_cast<const shortx8*>(
            (const char*)As + row * 128 + ((s * 64 + quad * 16) ^ swz(row)));
      }
      #pragma unroll
      for (int j = 0; j < 4; ++j) {
        const int row = wn + j * 16 + l16;
        bfr[j] = *reinterpret_cast<const shortx8*>(
            (const char*)Bs + row * 128 + ((s * 64 + quad * 16) ^ swz(row)));
      }
      #pragma unroll
      for (int i = 0; i < 4; ++i)
        #pragma unroll
        for (int j = 0; j < 4; ++j)
          acc[i][j] = __builtin_amdgcn_mfma_f32_16x16x32_bf16(af[i], bfr[j], acc[i][j], 0, 0, 0);
    }

    __syncthreads();
  }

  // ---- epilogue: C/D layout col=l16, row=quad*4+r (harness-verified mapping)
  float* outp = out + ((size_t)b * T_DIM + (size_t)mt * 128) * HID_DIM + nt * 128;
  const float* bp = bias + (size_t)c * HID_DIM + nt * 128;
  #pragma unroll
  for (int j = 0; j < 4; ++j) {
    const float bj = bp[wn + j * 16 + l16];
    #pragma unroll
    for (int i = 0; i < 4; ++i) {
      #pragma unroll
      for (int r = 0; r < 4; ++r) {
        const int m = wm + i * 16 + quad * 4 + r;
        outp[(size_t)m * HID_DIM + wn + j * 16 + l16] = acc[i][j][r] + bj;
      }
    }
  }
}

extern "C" void kernel_launch(void* const* d_in, const int* in_sizes, int n_in,
                              void* d_out, int out_size, void* d_ws, size_t ws_size,
                              hipStream_t stream) {
  const float* x    = (const float*)d_in[0];
  const int*   cat  = (const int*)d_in[1];
  const float* W    = (const float*)d_in[2];
  const float* bias = (const float*)d_in[3];
  float* out = (float*)d_out;

  // Single fused launch; d_ws deliberately untouched.
  dim3 grid(HID_DIM / 128, T_DIM / 128, B_DIM);   // (16, 2, 64) = 2048 blocks
  hipLaunchKernelGGL(cat_linear_fused_kernel, grid, dim3(256), 0, stream,
                     x, cat, W, bias, out);
}

// Round 5
// 503.329 us; speedup vs baseline: 1.1217x; 1.0868x over previous
//
#include <hip/hip_runtime.h>
#include <hip/hip_bf16.h>

#define NUM_CAT 32
#define IN_DIM 1024
#define HID_DIM 2048
#define T_DIM 256
#define B_DIM 64

typedef __attribute__((ext_vector_type(4))) float floatx4;
typedef __attribute__((ext_vector_type(8))) short shortx8;   // 8 bf16 (4 VGPRs)

// hardware packed conversion: v_cvt_pk_bf16_f32 (verified Round 4)
__device__ __forceinline__ unsigned pack2(float a, float b) {
  __hip_bfloat162 h2 = __float22bfloat162_rn(make_float2(a, b));
  unsigned u;
  __builtin_memcpy(&u, &h2, 4);
  return u;
}

// Extended XOR swizzle (verified Round 4): uniform 8-lane -> 8-slot mapping
// for A-write, B-write, A-read, B-read. Same XOR on write and read.
__device__ __forceinline__ int swz(int row) {
  return ((row & 7) << 4) ^ ((row & 8) << 2);
}

// =====================================================================
// Round 5: same verified tile/layout/epilogue as Round 4, new schedule:
//   - double-buffered LDS (2x32 KB), ONE barrier per K-step
//   - register prefetch: tile t+1 global loads issued BEFORE the barrier,
//     converted + ds_written at the top of iteration t+1 (T14 async-split;
//     reg loads are not drained by s_barrier, so they fly under compute)
//   - batch z remapped to (cat, idx)-sorted order: same-category blocks
//     become temporally adjacent and share W panels via L2/L3
// =====================================================================
__global__ __launch_bounds__(256) void cat_linear_fused_kernel(
    const float* __restrict__ x, const int* __restrict__ cat_ids,
    const float* __restrict__ W, const float* __restrict__ bias,
    float* __restrict__ out) {
  const int nt = blockIdx.x;   // 0..15  (hidden tiles)
  const int mt = blockIdx.y;   // 0..1   (token tiles)
  const int tid = threadIdx.x;

  // ---- category-sorted batch selection: b = index of the blockIdx.z-th
  // batch when batches are sorted by (cat, original index). pos is a
  // permutation of 0..63, so exactly one thread writes bsel.
  __shared__ int bsel;
  {
    const int i = tid & 63;
    const int ci = cat_ids[i];
    int pos = 0;
    for (int j = 0; j < 64; ++j) {
      const int cj = cat_ids[j];
      pos += (cj < ci || (cj == ci && j < i)) ? 1 : 0;
    }
    if (tid < 64 && pos == (int)blockIdx.z) bsel = i;
  }
  __syncthreads();
  const int b = bsel;
  const int c = cat_ids[b];

  // double-buffered LDS: 2 x (16 KB A + 16 KB B) = 64 KB
  __shared__ __attribute__((aligned(16))) unsigned short As[2][128 * 64];
  __shared__ __attribute__((aligned(16))) unsigned short Bs[2][128 * 64];

  const int lane = tid & 63;
  const int wv   = tid >> 6;         // wave 0..3 -> 2x2
  const int wm   = (wv >> 1) * 64;
  const int wn   = (wv & 1) * 64;
  const int l16  = lane & 15;
  const int quad = lane >> 4;

  // A staging: thread -> (row ar + i*32, k-bytes au*16..au*16+15)
  const int ar = tid >> 3;           // 0..31
  const int au = tid & 7;            // 16B unit within 128B row
  // B staging: thread -> (n = bn4..bn4+3, k = bk8..bk8+7)
  const int bn4 = (tid & 31) * 4;    // 0..124
  const int bk8 = (tid >> 5) * 8;    // 0..56

  const float* xb = x + ((size_t)b * T_DIM + (size_t)mt * 128) * IN_DIM;
  const float* Wc = W + (size_t)c * IN_DIM * HID_DIM + (size_t)nt * 128;

  floatx4 acc[4][4] = {};

  // prefetch registers (held across the barrier; consumed next iteration)
  float4 pa[8];   // A: 4 rows x 2 float4
  float4 pw[8];   // B: 8 k-rows x 1 float4

  auto issueA = [&](int ks) {
    const int k0 = ks * 64;
    #pragma unroll
    for (int i = 0; i < 4; ++i) {
      const float* ap = xb + (size_t)(i * 32 + ar) * IN_DIM + k0 + au * 8;
      pa[2 * i]     = *reinterpret_cast<const float4*>(ap);
      pa[2 * i + 1] = *reinterpret_cast<const float4*>(ap + 4);
    }
  };
  auto issueW = [&](int ks) {
    const float* wp = Wc + (size_t)(ks * 64 + bk8) * HID_DIM + bn4;
    #pragma unroll
    for (int r = 0; r < 8; ++r)
      pw[r] = *reinterpret_cast<const float4*>(wp + (size_t)r * HID_DIM);
  };

  // prologue: loads for tile 0 in flight
  issueA(0);
  issueW(0);

  for (int ks = 0; ks < IN_DIM / 64; ++ks) {
    unsigned short* Asb = As[ks & 1];
    unsigned short* Bsb = Bs[ks & 1];

    // ---- convert + ds_write tile ks (waits vmcnt on pa/pw at first use)
    #pragma unroll
    for (int i = 0; i < 4; ++i) {
      const int m = i * 32 + ar;
      union { shortx8 s8; unsigned u[4]; } pk;
      pk.u[0] = pack2(pa[2 * i].x, pa[2 * i].y);
      pk.u[1] = pack2(pa[2 * i].z, pa[2 * i].w);
      pk.u[2] = pack2(pa[2 * i + 1].x, pa[2 * i + 1].y);
      pk.u[3] = pack2(pa[2 * i + 1].z, pa[2 * i + 1].w);
      *reinterpret_cast<shortx8*>(
          (char*)Asb + m * 128 + ((au * 16) ^ swz(m))) = pk.s8;
    }
    {
      union { shortx8 s8; unsigned u[4]; } pk;
      // n = bn4 + 0
      pk.u[0] = pack2(pw[0].x, pw[1].x); pk.u[1] = pack2(pw[2].x, pw[3].x);
      pk.u[2] = pack2(pw[4].x, pw[5].x); pk.u[3] = pack2(pw[6].x, pw[7].x);
      *reinterpret_cast<shortx8*>(
          (char*)Bsb + (bn4 + 0) * 128 + ((bk8 * 2) ^ swz(bn4 + 0))) = pk.s8;
      // n = bn4 + 1
      pk.u[0] = pack2(pw[0].y, pw[1].y); pk.u[1] = pack2(pw[2].y, pw[3].y);
      pk.u[2] = pack2(pw[4].y, pw[5].y); pk.u[3] = pack2(pw[6].y, pw[7].y);
      *reinterpret_cast<shortx8*>(
          (char*)Bsb + (bn4 + 1) * 128 + ((bk8 * 2) ^ swz(bn4 + 1))) = pk.s8;
      // n = bn4 + 2
      pk.u[0] = pack2(pw[0].z, pw[1].z); pk.u[1] = pack2(pw[2].z, pw[3].z);
      pk.u[2] = pack2(pw[4].z, pw[5].z); pk.u[3] = pack2(pw[6].z, pw[7].z);
      *reinterpret_cast<shortx8*>(
          (char*)Bsb + (bn4 + 2) * 128 + ((bk8 * 2) ^ swz(bn4 + 2))) = pk.s8;
      // n = bn4 + 3
      pk.u[0] = pack2(pw[0].w, pw[1].w); pk.u[1] = pack2(pw[2].w, pw[3].w);
      pk.u[2] = pack2(pw[4].w, pw[5].w); pk.u[3] = pack2(pw[6].w, pw[7].w);
      *reinterpret_cast<shortx8*>(
          (char*)Bsb + (bn4 + 3) * 128 + ((bk8 * 2) ^ swz(bn4 + 3))) = pk.s8;
    }

    // ---- issue next tile's global loads BEFORE the barrier (prefetch).
    // They stay in flight across s_barrier (reg loads aren't drained) and
    // complete under the MFMA phase; consumed at next iteration's convert.
    if (ks < IN_DIM / 64 - 1) {
      issueA(ks + 1);
      issueW(ks + 1);
    }

    __syncthreads();   // single barrier per K-step (dbuf makes it sufficient)

    // ---- fragments + MFMA (addressing = verified Round-4 pattern)
    #pragma unroll
    for (int s = 0; s < 2; ++s) {
      shortx8 af[4], bfr[4];
      #pragma unroll
      for (int i = 0; i < 4; ++i) {
        const int row = wm + i * 16 + l16;
        af[i] = *reinterpret_cast<const shortx8*>(
            (const char*)Asb + row * 128 + ((s * 64 + quad * 16) ^ swz(row)));
      }
      #pragma unroll
      for (int j = 0; j < 4; ++j) {
        const int row = wn + j * 16 + l16;
        bfr[j] = *reinterpret_cast<const shortx8*>(
            (const char*)Bsb + row * 128 + ((s * 64 + quad * 16) ^ swz(row)));
      }
      #pragma unroll
      for (int i = 0; i < 4; ++i)
        #pragma unroll
        for (int j = 0; j < 4; ++j)
          acc[i][j] = __builtin_amdgcn_mfma_f32_16x16x32_bf16(af[i], bfr[j], acc[i][j], 0, 0, 0);
    }
    // no trailing barrier: next iteration writes the OTHER buffer, and its
    // barrier separates those writes from any wave still reading this one.
  }

  // ---- epilogue: C/D layout col=l16, row=quad*4+r (harness-verified mapping)
  float* outp = out + ((size_t)b * T_DIM + (size_t)mt * 128) * HID_DIM + nt * 128;
  const float* bp = bias + (size_t)c * HID_DIM + nt * 128;
  #pragma unroll
  for (int j = 0; j < 4; ++j) {
    const float bj = bp[wn + j * 16 + l16];
    #pragma unroll
    for (int i = 0; i < 4; ++i) {
      #pragma unroll
      for (int r = 0; r < 4; ++r) {
        const int m = wm + i * 16 + quad * 4 + r;
        outp[(size_t)m * HID_DIM + wn + j * 16 + l16] = acc[i][j][r] + bj;
      }
    }
  }
}

extern "C" void kernel_launch(void* const* d_in, const int* in_sizes, int n_in,
                              void* d_out, int out_size, void* d_ws, size_t ws_size,
                              hipStream_t stream) {
  const float* x    = (const float*)d_in[0];
  const int*   cat  = (const int*)d_in[1];
  const float* W    = (const float*)d_in[2];
  const float* bias = (const float*)d_in[3];
  float* out = (float*)d_out;

  // Single fused launch; d_ws deliberately untouched.
  dim3 grid(HID_DIM / 128, T_DIM / 128, B_DIM);   // (16, 2, 64) = 2048 blocks
  hipLaunchKernelGGL(cat_linear_fused_kernel, grid, dim3(256), 0, stream,
                     x, cat, W, bias, out);
}